// Round 11
// baseline (353.585 us; speedup 1.0000x reference)
//
#include <hip/hip_runtime.h>

// LSTM B=2048,T=512,I=5,H=128 + linear -> [B,1], fp32 in/out.
// Round 11 = r10 (352us: 256 blocks x 8 batches, NT=512, row-permuted direct
// cell ownership, dbuf h, 1 barrier/step) + two MFMA-phase cuts:
//  (1) x/bias chunk via legacy v_mfma_f32_16x16x16f16 (K=16 covers the 6 real
//      k-cols; ~9.7 vs 19.4 cyc/SIMD): MFMA issue 776 -> 698 cyc/SIMD-step.
//      A-side: ds_read_b64 of xs at +q*4; q>=2 / pad-row garbage killed by
//      zero W-side cols (same mechanism r10 verified).
//  (2) gate-pair interleave: [i,f chains] -> sigma(i),sigma(f) trans -> [g,o
//      chains] -> rest. i/f trans co-issue with ~390cyc of g/o MFMA issue
//      instead of serializing after the full MFMA phase.
// Step model (measured r10 = 1510c): 120 ds latency + 698 MFMA + (320 trans
// issue - overlap) + barrier -> ~1350c predicted.
// Known-dead-ends (measured): BT=16 halves CUs (r3/r7/r8); 1024-thr blocks
// pin VGPR at 64 -> spill (r8/r9); K-split pacc exchange = +2e7 conflicts (r7).

#define HH 128
#define II 5
#define TT 512
#define BT 8
#define NT 512
#define KS 136             // hbuf row stride in f16
#define XT (TT * 8 + 8)    // xs per-batch stride in f16
#define HB (16 * KS)       // hbuf buffer stride in f16 elems

typedef __attribute__((ext_vector_type(8))) _Float16 half8;
typedef __attribute__((ext_vector_type(4))) _Float16 half4;
typedef __attribute__((ext_vector_type(4))) float f32x4;

#define SIG(u) __builtin_amdgcn_rcpf(1.0f + __builtin_amdgcn_exp2f(u))
#define MF32(A, B, C) __builtin_amdgcn_mfma_f32_16x16x32_f16((A), (B), (C), 0, 0, 0)
#define MF16(A, B, C) __builtin_amdgcn_mfma_f32_16x16x16f16((A), (B), (C), 0, 0, 0)

// One timestep. PB = h read buffer (compile-time 0/1), LAST = peeled final.
#define STEP(PB, LAST) {                                                        \
    const _Float16* hp = hrd + (PB) * HB;                                       \
    ah0 = *reinterpret_cast<const half8*>(hp);                                  \
    ah1 = *reinterpret_cast<const half8*>(hp + 32);                             \
    ah2 = *reinterpret_cast<const half8*>(hp + 64);                             \
    ah3 = *reinterpret_cast<const half8*>(hp + 96);                             \
    /* gates i,f first */                                                       \
    f32x4 a0 = MF16(ax4, wfx[0], zero4);                                        \
    f32x4 a1 = MF16(ax4, wfx[1], zero4);                                        \
    a0 = MF32(ah0, wf[0][0], a0); a1 = MF32(ah0, wf[1][0], a1);                 \
    a0 = MF32(ah1, wf[0][1], a0); a1 = MF32(ah1, wf[1][1], a1);                 \
    a0 = MF32(ah2, wf[0][2], a0); a1 = MF32(ah2, wf[1][2], a1);                 \
    a0 = MF32(ah3, wf[0][3], a0); a1 = MF32(ah3, wf[1][3], a1);                 \
    /* i,f trans issue while g,o chains occupy the MFMA pipe */                 \
    float iv0 = SIG(a0[0]);                                                     \
    float iv1 = SIG(a0[1]);                                                     \
    float fv0 = SIG(a1[0]);                                                     \
    float fv1 = SIG(a1[1]);                                                     \
    f32x4 a2 = MF16(ax4, wfx[2], zero4);                                        \
    f32x4 a3 = MF16(ax4, wfx[3], zero4);                                        \
    a2 = MF32(ah0, wf[2][0], a2); a3 = MF32(ah0, wf[3][0], a3);                 \
    a2 = MF32(ah1, wf[2][1], a2); a3 = MF32(ah1, wf[3][1], a3);                 \
    a2 = MF32(ah2, wf[2][2], a2); a3 = MF32(ah2, wf[3][2], a3);                 \
    a2 = MF32(ah3, wf[2][3], a2); a3 = MF32(ah3, wf[3][3], a3);                 \
    if (!(LAST)) {                      /* prefetch ax(t+1): static xs */       \
        xcur += xinc;                                                           \
        ax4 = *reinterpret_cast<const half4*>(xcur);                            \
    }                                                                           \
    float gv0 = 1.0f - 2.0f * SIG(a2[0]);                                       \
    float ov0 = SIG(a3[0]);                                                     \
    cc0 = fv0 * cc0 + iv0 * gv0;                                                \
    float hv0 = ov0 * (1.0f - 2.0f * SIG(2.88539008f * cc0));                   \
    float gv1 = 1.0f - 2.0f * SIG(a2[1]);                                       \
    float ov1 = SIG(a3[1]);                                                     \
    cc1 = fv1 * cc1 + iv1 * gv1;                                                \
    float hv1 = ov1 * (1.0f - 2.0f * SIG(2.88539008f * cc1));                   \
    if (LAST) {                                                                 \
        hsc[bcell][hcol] = hv0; hsc[bcell + 1][hcol] = hv1;                     \
    } else {                                                                    \
        _Float16* wp = hwr + ((PB) ^ 1) * HB;                                   \
        wp[0]  = (_Float16)hv0;                                                 \
        wp[KS] = (_Float16)hv1;                                                 \
    }                                                                           \
    __syncthreads();                                                            \
}

__global__ __launch_bounds__(NT)
__attribute__((amdgpu_waves_per_eu(2, 2)))   // 256-VGPR budget: spill guard
void lstm_r11(const float* __restrict__ x,      // [B,T,I]
              const float* __restrict__ W_ih,   // [4H,I]
              const float* __restrict__ W_hh,   // [4H,H]
              const float* __restrict__ b_ih,   // [4H]
              const float* __restrict__ b_hh,   // [4H]
              const float* __restrict__ W_lin,  // [H]
              const float* __restrict__ b_lin,  // [1]
              float* __restrict__ out,          // [B]
              int B)
{
    __shared__ __align__(16) _Float16 hbuf[2][16][KS];  // rows 2,3 mod 4 stay 0
    __shared__ __align__(16) _Float16 zrow[KS];         // zeros for pad-row lanes
    __shared__ __align__(16) _Float16 xs[BT * XT];      // 65.7 KB staged x (f16)
    __shared__ float hsc[BT][HH + 4];                   // final fp32 h

    const int tid  = threadIdx.x;
    const int b0   = blockIdx.x * BT;
    const int lane = tid & 63;
    const int w    = tid >> 6;        // 0..7 -> col group
    const int n    = lane & 15;       // A row index / D col
    const int q    = lane >> 4;
    const int q8   = q * 8;
    const int hcol = w * 16 + n;      // this wave's gate columns

    // ---- W_hh frags, f16, B-layout (lane holds W^T[k=q8+e][col n]), scaled --
    half8 wf[4][4];
    half4 wfx[4];                     // x/bias chunk, K=16: k = q*4+e
    #pragma unroll
    for (int g = 0; g < 4; ++g) {
        const float sc = (g == 2) ? 2.88539008f : -1.44269504f;
        const int j = g * HH + hcol;
        #pragma unroll
        for (int kc = 0; kc < 4; ++kc) {
            const float* p = W_hh + (size_t)j * HH + kc * 32 + q8;
            #pragma unroll
            for (int e = 0; e < 8; ++e) wf[g][kc][e] = (_Float16)(p[e] * sc);
        }
        #pragma unroll
        for (int e = 0; e < 4; ++e) {
            const int k = q * 4 + e;
            float v = 0.0f;
            if (k < II)       v = W_ih[j * II + k];
            else if (k == II) v = b_ih[j] + b_hh[j];
            wfx[g][e] = (_Float16)(v * sc);
        }
    }

    // ---- zero LDS -----------------------------------------------------------
    for (int idx = tid; idx < 2 * 16 * KS; idx += NT)
        (&hbuf[0][0][0])[idx] = (_Float16)0.0f;
    if (tid < KS) zrow[tid] = (_Float16)0.0f;
    for (int idx = tid; idx < BT * XT; idx += NT)
        xs[idx] = (_Float16)0.0f;
    __syncthreads();

    // ---- stage x (f16) + constant-1.0 bias column in slot 5 -----------------
    {
        const int lb = tid & 63, bb = tid >> 6;     // 64 threads per batch
        if (b0 + bb < B) {
            const float* xb = x + (size_t)(b0 + bb) * TT * II;
            for (int e = lb * 4; e < TT * II; e += 256) {
                float4 v = *reinterpret_cast<const float4*>(xb + e);
                float vv[4] = {v.x, v.y, v.z, v.w};
                #pragma unroll
                for (int u = 0; u < 4; ++u) {
                    const int ee = e + u;
                    xs[bb * XT + (ee / 5) * 8 + (ee % 5)] = (_Float16)vv[u];
                }
            }
        }
        for (int s = tid; s < BT * TT; s += NT)
            xs[(s >> 9) * XT + (s & 511) * 8 + 5] = (_Float16)1.0f;
    }
    __syncthreads();

    // ---- loop-invariant state ----------------------------------------------
    // Row permutation (r10): batch b -> A-row rho(b) = (b>>1)*4 + (b&1);
    // C/D rows q*4+{0,1} = batches {2q, 2q+1} -> direct cell ownership.
    const int bcell = 2 * q;
    float cc0 = 0.f, cc1 = 0.f;
    const f32x4 zero4 = {0.f, 0.f, 0.f, 0.f};
    const bool xreal = ((n & 2) == 0);
    const int  bofn  = (n >> 2) * 2 + (n & 1);      // batch carried by A-row n
    const _Float16* hrd  = &hbuf[0][n][0] + q8;     // unconditional (pad rows = 0)
    _Float16*       hwr  = &hbuf[0][q * 4][0] + hcol;
    // x A-frag (K=16): lane supplies k=q*4+e -> xs[... t*8 + q*4]; garbage at
    // k>=8 (q>=2 reads next-t slots) multiplies zero W cols -> harmless.
    const _Float16* xcur = xreal ? (&xs[bofn * XT] + q * 4) : (&zrow[0] + q * 4);
    const int       xinc = xreal ? 8 : 0;

    half8 ah0, ah1, ah2, ah3;
    half4 ax4 = *reinterpret_cast<const half4*>(xcur);   // t=0 preload

    #pragma unroll 1
    for (int k = 0; k < (TT - 2) / 2; ++k) {
        STEP(0, false);
        STEP(1, false);
    }
    STEP(0, false);     // t = 510
    STEP(1, true);      // t = 511, peeled: fp32 hsc write, no prefetch

    // ---- epilogue: out[b0+w] = hsc[w,:] . W_lin + b_lin ---------------------
    float p = hsc[w][lane] * W_lin[lane] + hsc[w][lane + 64] * W_lin[lane + 64];
    #pragma unroll
    for (int off = 32; off > 0; off >>= 1) p += __shfl_down(p, off, 64);
    if (lane == 0 && (b0 + w) < B) out[b0 + w] = p + b_lin[0];
}

extern "C" void kernel_launch(void* const* d_in, const int* in_sizes, int n_in,
                              void* d_out, int out_size, void* d_ws, size_t ws_size,
                              hipStream_t stream) {
    const float* x     = (const float*)d_in[0];
    const float* W_ih  = (const float*)d_in[1];
    const float* W_hh  = (const float*)d_in[2];
    const float* b_ih  = (const float*)d_in[3];
    const float* b_hh  = (const float*)d_in[4];
    const float* W_lin = (const float*)d_in[5];
    const float* b_lin = (const float*)d_in[6];
    float* out = (float*)d_out;

    const int B = in_sizes[0] / (TT * II);          // 2048
    const int grid = (B + BT - 1) / BT;             // 256 blocks, 1 per CU
    lstm_r11<<<grid, NT, 0, stream>>>(x, W_ih, W_hh, b_ih, b_hh,
                                      W_lin, b_lin, out, B);
}

// Round 12
// 344.383 us; speedup vs baseline: 1.0267x; 1.0267x over previous
//
#include <hip/hip_runtime.h>

// LSTM B=2048,T=512,I=5,H=128 + linear -> [B,1], fp32 in/out.
// Round 12 = r11 (353us) + explicit sched_group_barrier interleave. r11's
// source-ordered [i,f MFMA -> i,f trans -> g,o MFMA] was neutral: the compiler
// hoists all 20 MFMAs together, so the sigmoids serialize after the full MFMA
// phase. Force the schedule per step region:
//   [4 ds_read_b128] [10 MFMA i,f] [14 VALU/TRANS: sig(i),sig(f)] [10 MFMA g,o]
// so the i/f sigmoid chains execute UNDER g/o's ~390cyc of MFMA issue.
// Masks: 0x100 DS-read, 0x8 MFMA, 0x402 VALU|TRANS (hedge for gfx950 trans
// class). Soft mechanism: unmatched groups degrade to no-op, not misschedule.
// Everything else proven/unchanged: 256 blocks x 8 batches, NT=512, row-
// permuted direct cell ownership (no shuffles), dbuf h + 1 barrier/step,
// K=16 x/bias MFMA, folded activation scales, peeled last step, f16 operands
// (absmax 4.882812e-4 exactly), waves_per_eu(2,2) spill guard.
// Measured dead-ends: BT=16 halves CUs (r3/r7/r8); 1024-thr blocks pin VGPR
// at 64 -> spill (r8/r9); BT=4 2-blocks/CU doubles MFMA padding (modeled);
// K-split pacc exchange +2e7 conflicts (r7).

#define HH 128
#define II 5
#define TT 512
#define BT 8
#define NT 512
#define KS 136             // hbuf row stride in f16
#define XT (TT * 8 + 8)    // xs per-batch stride in f16
#define HB (16 * KS)       // hbuf buffer stride in f16 elems

typedef __attribute__((ext_vector_type(8))) _Float16 half8;
typedef __attribute__((ext_vector_type(4))) _Float16 half4;
typedef __attribute__((ext_vector_type(4))) float f32x4;

#define SIG(u) __builtin_amdgcn_rcpf(1.0f + __builtin_amdgcn_exp2f(u))
#define MF32(A, B, C) __builtin_amdgcn_mfma_f32_16x16x32_f16((A), (B), (C), 0, 0, 0)
#define MF16(A, B, C) __builtin_amdgcn_mfma_f32_16x16x16f16((A), (B), (C), 0, 0, 0)
#define SGB(m, n) __builtin_amdgcn_sched_group_barrier((m), (n), 0)

// One timestep. PB = h read buffer (compile-time 0/1), LAST = peeled final.
#define STEP(PB, LAST) {                                                        \
    const _Float16* hp = hrd + (PB) * HB;                                       \
    ah0 = *reinterpret_cast<const half8*>(hp);                                  \
    ah1 = *reinterpret_cast<const half8*>(hp + 32);                             \
    ah2 = *reinterpret_cast<const half8*>(hp + 64);                             \
    ah3 = *reinterpret_cast<const half8*>(hp + 96);                             \
    /* gates i,f first */                                                       \
    f32x4 a0 = MF16(ax4, wfx[0], zero4);                                        \
    f32x4 a1 = MF16(ax4, wfx[1], zero4);                                        \
    a0 = MF32(ah0, wf[0][0], a0); a1 = MF32(ah0, wf[1][0], a1);                 \
    a0 = MF32(ah1, wf[0][1], a0); a1 = MF32(ah1, wf[1][1], a1);                 \
    a0 = MF32(ah2, wf[0][2], a0); a1 = MF32(ah2, wf[1][2], a1);                 \
    a0 = MF32(ah3, wf[0][3], a0); a1 = MF32(ah3, wf[1][3], a1);                 \
    /* i,f trans intended to issue while g,o chains occupy the MFMA pipe */     \
    float iv0 = SIG(a0[0]);                                                     \
    float iv1 = SIG(a0[1]);                                                     \
    float fv0 = SIG(a1[0]);                                                     \
    float fv1 = SIG(a1[1]);                                                     \
    f32x4 a2 = MF16(ax4, wfx[2], zero4);                                        \
    f32x4 a3 = MF16(ax4, wfx[3], zero4);                                        \
    a2 = MF32(ah0, wf[2][0], a2); a3 = MF32(ah0, wf[3][0], a3);                 \
    a2 = MF32(ah1, wf[2][1], a2); a3 = MF32(ah1, wf[3][1], a3);                 \
    a2 = MF32(ah2, wf[2][2], a2); a3 = MF32(ah2, wf[3][2], a3);                 \
    a2 = MF32(ah3, wf[2][3], a2); a3 = MF32(ah3, wf[3][3], a3);                 \
    if (!(LAST)) {                      /* prefetch ax(t+1): static xs */       \
        xcur += xinc;                                                           \
        ax4 = *reinterpret_cast<const half4*>(xcur);                            \
    }                                                                           \
    float gv0 = 1.0f - 2.0f * SIG(a2[0]);                                       \
    float ov0 = SIG(a3[0]);                                                     \
    cc0 = fv0 * cc0 + iv0 * gv0;                                                \
    float hv0 = ov0 * (1.0f - 2.0f * SIG(2.88539008f * cc0));                   \
    float gv1 = 1.0f - 2.0f * SIG(a2[1]);                                       \
    float ov1 = SIG(a3[1]);                                                     \
    cc1 = fv1 * cc1 + iv1 * gv1;                                                \
    float hv1 = ov1 * (1.0f - 2.0f * SIG(2.88539008f * cc1));                   \
    if (LAST) {                                                                 \
        hsc[bcell][hcol] = hv0; hsc[bcell + 1][hcol] = hv1;                     \
    } else {                                                                    \
        _Float16* wp = hwr + ((PB) ^ 1) * HB;                                   \
        wp[0]  = (_Float16)hv0;                                                 \
        wp[KS] = (_Float16)hv1;                                                 \
    }                                                                           \
    /* ---- scheduling groups for this region (soft; no-op if unmatched) ---- */\
    SGB(0x100, 4);     /* 4x ds_read_b128 (ah) */                               \
    SGB(0x008, 10);    /* i,f MFMA chains */                                    \
    SGB(0x402, 14);    /* i,f sigmoids (VALU|TRANS) under g,o MFMA issue */     \
    SGB(0x008, 10);    /* g,o MFMA chains */                                    \
    __syncthreads();                                                            \
}

__global__ __launch_bounds__(NT)
__attribute__((amdgpu_waves_per_eu(2, 2)))   // 256-VGPR budget: spill guard
void lstm_r12(const float* __restrict__ x,      // [B,T,I]
              const float* __restrict__ W_ih,   // [4H,I]
              const float* __restrict__ W_hh,   // [4H,H]
              const float* __restrict__ b_ih,   // [4H]
              const float* __restrict__ b_hh,   // [4H]
              const float* __restrict__ W_lin,  // [H]
              const float* __restrict__ b_lin,  // [1]
              float* __restrict__ out,          // [B]
              int B)
{
    __shared__ __align__(16) _Float16 hbuf[2][16][KS];  // rows 2,3 mod 4 stay 0
    __shared__ __align__(16) _Float16 zrow[KS];         // zeros for pad-row lanes
    __shared__ __align__(16) _Float16 xs[BT * XT];      // 65.7 KB staged x (f16)
    __shared__ float hsc[BT][HH + 4];                   // final fp32 h

    const int tid  = threadIdx.x;
    const int b0   = blockIdx.x * BT;
    const int lane = tid & 63;
    const int w    = tid >> 6;        // 0..7 -> col group
    const int n    = lane & 15;       // A row index / D col
    const int q    = lane >> 4;
    const int q8   = q * 8;
    const int hcol = w * 16 + n;      // this wave's gate columns

    // ---- W_hh frags, f16, B-layout (lane holds W^T[k=q8+e][col n]), scaled --
    half8 wf[4][4];
    half4 wfx[4];                     // x/bias chunk, K=16: k = q*4+e
    #pragma unroll
    for (int g = 0; g < 4; ++g) {
        const float sc = (g == 2) ? 2.88539008f : -1.44269504f;
        const int j = g * HH + hcol;
        #pragma unroll
        for (int kc = 0; kc < 4; ++kc) {
            const float* p = W_hh + (size_t)j * HH + kc * 32 + q8;
            #pragma unroll
            for (int e = 0; e < 8; ++e) wf[g][kc][e] = (_Float16)(p[e] * sc);
        }
        #pragma unroll
        for (int e = 0; e < 4; ++e) {
            const int k = q * 4 + e;
            float v = 0.0f;
            if (k < II)       v = W_ih[j * II + k];
            else if (k == II) v = b_ih[j] + b_hh[j];
            wfx[g][e] = (_Float16)(v * sc);
        }
    }

    // ---- zero LDS -----------------------------------------------------------
    for (int idx = tid; idx < 2 * 16 * KS; idx += NT)
        (&hbuf[0][0][0])[idx] = (_Float16)0.0f;
    if (tid < KS) zrow[tid] = (_Float16)0.0f;
    for (int idx = tid; idx < BT * XT; idx += NT)
        xs[idx] = (_Float16)0.0f;
    __syncthreads();

    // ---- stage x (f16) + constant-1.0 bias column in slot 5 -----------------
    {
        const int lb = tid & 63, bb = tid >> 6;     // 64 threads per batch
        if (b0 + bb < B) {
            const float* xb = x + (size_t)(b0 + bb) * TT * II;
            for (int e = lb * 4; e < TT * II; e += 256) {
                float4 v = *reinterpret_cast<const float4*>(xb + e);
                float vv[4] = {v.x, v.y, v.z, v.w};
                #pragma unroll
                for (int u = 0; u < 4; ++u) {
                    const int ee = e + u;
                    xs[bb * XT + (ee / 5) * 8 + (ee % 5)] = (_Float16)vv[u];
                }
            }
        }
        for (int s = tid; s < BT * TT; s += NT)
            xs[(s >> 9) * XT + (s & 511) * 8 + 5] = (_Float16)1.0f;
    }
    __syncthreads();

    // ---- loop-invariant state ----------------------------------------------
    // Row permutation (r10): batch b -> A-row rho(b) = (b>>1)*4 + (b&1);
    // C/D rows q*4+{0,1} = batches {2q, 2q+1} -> direct cell ownership.
    const int bcell = 2 * q;
    float cc0 = 0.f, cc1 = 0.f;
    const f32x4 zero4 = {0.f, 0.f, 0.f, 0.f};
    const bool xreal = ((n & 2) == 0);
    const int  bofn  = (n >> 2) * 2 + (n & 1);      // batch carried by A-row n
    const _Float16* hrd  = &hbuf[0][n][0] + q8;     // unconditional (pad rows = 0)
    _Float16*       hwr  = &hbuf[0][q * 4][0] + hcol;
    // x A-frag (K=16): lane supplies k=q*4+e; garbage at k>=8 multiplies zero
    // W cols -> harmless (verified: r11 absmax identical to r10).
    const _Float16* xcur = xreal ? (&xs[bofn * XT] + q * 4) : (&zrow[0] + q * 4);
    const int       xinc = xreal ? 8 : 0;

    half8 ah0, ah1, ah2, ah3;
    half4 ax4 = *reinterpret_cast<const half4*>(xcur);   // t=0 preload

    #pragma unroll 1
    for (int k = 0; k < (TT - 2) / 2; ++k) {
        STEP(0, false);
        STEP(1, false);
    }
    STEP(0, false);     // t = 510
    STEP(1, true);      // t = 511, peeled: fp32 hsc write, no prefetch

    // ---- epilogue: out[b0+w] = hsc[w,:] . W_lin + b_lin ---------------------
    float p = hsc[w][lane] * W_lin[lane] + hsc[w][lane + 64] * W_lin[lane + 64];
    #pragma unroll
    for (int off = 32; off > 0; off >>= 1) p += __shfl_down(p, off, 64);
    if (lane == 0 && (b0 + w) < B) out[b0 + w] = p + b_lin[0];
}

extern "C" void kernel_launch(void* const* d_in, const int* in_sizes, int n_in,
                              void* d_out, int out_size, void* d_ws, size_t ws_size,
                              hipStream_t stream) {
    const float* x     = (const float*)d_in[0];
    const float* W_ih  = (const float*)d_in[1];
    const float* W_hh  = (const float*)d_in[2];
    const float* b_ih  = (const float*)d_in[3];
    const float* b_hh  = (const float*)d_in[4];
    const float* W_lin = (const float*)d_in[5];
    const float* b_lin = (const float*)d_in[6];
    float* out = (float*)d_out;

    const int B = in_sizes[0] / (TT * II);          // 2048
    const int grid = (B + BT - 1) / BT;             // 256 blocks, 1 per CU
    lstm_r12<<<grid, NT, 0, stream>>>(x, W_ih, W_hh, b_ih, b_hh,
                                      W_lin, b_lin, out, B);
}